// Round 1
// baseline (68232.147 us; speedup 1.0000x reference)
//
#include <hip/hip_runtime.h>
#include <hip/hip_cooperative_groups.h>
#include <math.h>

namespace cg = cooperative_groups;

#define SEQ    2048
#define BATCH  32
#define IN_DIM 512
#define HID    512
#define GATES  (4*HID)   // 2048

// ---------------------------------------------------------------------------
// x_proj GEMM:  xp[m][n] = sum_k x[m][k]*Wih[n][k] + bih[n] + bhh[n]
// m = t*32+b (chunk-local), NT layout (both K-contiguous). 128x128 tile,
// 8x8 microtile, K-chunk 16.
// ---------------------------------------------------------------------------
__global__ __launch_bounds__(256) void xproj_kernel(
    const float* __restrict__ x,     // [M][512] (already offset to chunk)
    const float* __restrict__ Wih,   // [2048][512]
    const float* __restrict__ bih,
    const float* __restrict__ bhh,
    float* __restrict__ xp,          // [M][2048]
    int M)
{
    __shared__ float As[16][132];
    __shared__ float Bs[16][132];
    const int tid = threadIdx.x;
    const int nb = blockIdx.x & 15;
    const int mb = blockIdx.x >> 4;
    const int m0 = mb * 128, n0 = nb * 128;
    const int tx = tid & 15, ty = tid >> 4;

    float acc[8][8];
#pragma unroll
    for (int i = 0; i < 8; ++i)
#pragma unroll
        for (int j = 0; j < 8; ++j) acc[i][j] = 0.f;

    for (int kc = 0; kc < 512; kc += 16) {
#pragma unroll
        for (int h = 0; h < 2; ++h) {
            int f4 = tid + 256 * h;
            int r = f4 >> 2, u = f4 & 3;
            float4 va = *(const float4*)(x + (size_t)(m0 + r) * 512 + kc + 4 * u);
            As[4*u+0][r] = va.x; As[4*u+1][r] = va.y;
            As[4*u+2][r] = va.z; As[4*u+3][r] = va.w;
            float4 vb = *(const float4*)(Wih + (size_t)(n0 + r) * 512 + kc + 4 * u);
            Bs[4*u+0][r] = vb.x; Bs[4*u+1][r] = vb.y;
            Bs[4*u+2][r] = vb.z; Bs[4*u+3][r] = vb.w;
        }
        __syncthreads();
#pragma unroll
        for (int kk = 0; kk < 16; ++kk) {
            float4 a0 = *(const float4*)&As[kk][tx * 8];
            float4 a1 = *(const float4*)&As[kk][tx * 8 + 4];
            float4 b0 = *(const float4*)&Bs[kk][ty * 8];
            float4 b1 = *(const float4*)&Bs[kk][ty * 8 + 4];
            float av[8] = {a0.x,a0.y,a0.z,a0.w,a1.x,a1.y,a1.z,a1.w};
            float bv[8] = {b0.x,b0.y,b0.z,b0.w,b1.x,b1.y,b1.z,b1.w};
#pragma unroll
            for (int i = 0; i < 8; ++i)
#pragma unroll
                for (int j = 0; j < 8; ++j) acc[i][j] += av[i] * bv[j];
        }
        __syncthreads();
    }

    float bias[8];
#pragma unroll
    for (int j = 0; j < 8; ++j) {
        int n = n0 + ty * 8 + j;
        bias[j] = bih[n] + bhh[n];
    }
#pragma unroll
    for (int i = 0; i < 8; ++i) {
        size_t base = (size_t)(m0 + tx * 8 + i) * GATES + n0 + ty * 8;
        float4 v0 = make_float4(acc[i][0]+bias[0], acc[i][1]+bias[1],
                                acc[i][2]+bias[2], acc[i][3]+bias[3]);
        float4 v1 = make_float4(acc[i][4]+bias[4], acc[i][5]+bias[5],
                                acc[i][6]+bias[6], acc[i][7]+bias[7]);
        *(float4*)(xp + base)     = v0;
        *(float4*)(xp + base + 4) = v1;
    }
}

// ---------------------------------------------------------------------------
// Persistent cooperative LSTM scan.
// Grid 256 WGs x 256 thr. WG w: hidden slice [8a,8a+8) (a=w>>2), batch slice
// [8bq,8bq+8) (bq=w&3). Thread: gate=tid>>6, bgl=(lane>>5) (4-batch half),
// kg=lane&31 (k range [16kg,16kg+16)). W_hh slice held in registers
// (8 rows x 16 k, permuted to match LDS swizzle). Per step:
//   stage h (global [2][4][512][8] -> LDS swizzled) ; 512 FMA/thread ;
//   32-lane index-descending shuffle reduction ; gates via LDS ; elementwise ;
//   write h to hs + double-buffered global h ; grid.sync().
// ---------------------------------------------------------------------------
__global__ __launch_bounds__(256) void lstm_coop(
    const float* __restrict__ Whh,   // [2048][512]
    const float* __restrict__ xp,    // [nsteps][32][2048]
    float* __restrict__ hbuf,        // [2][4][512][8]
    float* __restrict__ cbuf,        // [32][512]
    float* __restrict__ out_hs,      // [2048][32][512]
    int t0, int nsteps)
{
    cg::grid_group grid = cg::this_grid();
    const int w    = blockIdx.x;
    const int a    = w >> 2;
    const int bq   = w & 3;
    const int tid  = threadIdx.x;
    const int gate = tid >> 6;
    const int lane = tid & 63;
    const int bgl  = lane >> 5;
    const int kg   = lane & 31;
    const int hid0 = 8 * a;

    __shared__ float h_t[512 * 8];     // word(k,b) = 8*(k ^ ((k>>4)&3)) + b
    __shared__ float gbuf[4][64];

    // Load W_hh slice into registers, k-permuted to match LDS swizzle:
    // wreg[i][s] = Whh[row_i][16kg + (s ^ (kg&3))]
    float wreg[8][16];
    {
        const int kx = kg & 3;
#pragma unroll
        for (int i = 0; i < 8; ++i) {
            const float* wr = Whh + (size_t)(512 * gate + hid0 + i) * 512 + 16 * kg;
#pragma unroll
            for (int s = 0; s < 16; ++s) wreg[i][s] = wr[s ^ kx];
        }
    }

    // c state: one value per thread for tid<64: (i=(tid&31)>>2, j=tid&3)
    float c_reg = 0.f;
    if (tid < 64) {
        int i = (tid & 31) >> 2, j = tid & 3;
        int b = 8 * bq + 4 * (tid >> 5) + j;
        c_reg = cbuf[(size_t)b * HID + hid0 + i];
    }

    for (int t = t0; t < t0 + nsteps; ++t) {
        // ---- stage h slice (our 8 batches, all 512 k) into swizzled LDS
        const float* hsrc = hbuf + (size_t)(t & 1) * 16384 + (size_t)bq * 4096;
#pragma unroll
        for (int u = 0; u < 4; ++u) {
            int f = tid * 16 + u * 4;
            float4 v = *(const float4*)(hsrc + f);
            int k = f >> 3, bh = (f >> 2) & 1;
            int kp = k ^ ((k >> 4) & 3);
            *(float4*)&h_t[kp * 8 + bh * 4] = v;
        }
        __syncthreads();

        // ---- partial dot products: 8 rows x 4 batches x 16 k
        float acc[32];
#pragma unroll
        for (int m = 0; m < 32; ++m) acc[m] = 0.f;
        const int kbase = 16 * kg;
#pragma unroll
        for (int s = 0; s < 16; ++s) {
            float4 hv = *(const float4*)&h_t[(kbase + s) * 8 + 4 * bgl];
#pragma unroll
            for (int i = 0; i < 8; ++i) {
                acc[i*4+0] += wreg[i][s] * hv.x;
                acc[i*4+1] += wreg[i][s] * hv.y;
                acc[i*4+2] += wreg[i][s] * hv.z;
                acc[i*4+3] += wreg[i][s] * hv.w;
            }
        }

        // ---- index-descending butterfly over kg: lane kg ends with sum of acc[kg]
        {
            int sel = (kg >> 4) & 1;
#pragma unroll
            for (int m = 0; m < 16; ++m) {
                float mine = sel ? acc[m+16] : acc[m];
                float send = sel ? acc[m]    : acc[m+16];
                acc[m] = mine + __shfl_xor(send, 16, 64);
            }
        }
        {
            int sel = (kg >> 3) & 1;
#pragma unroll
            for (int m = 0; m < 8; ++m) {
                float mine = sel ? acc[m+8] : acc[m];
                float send = sel ? acc[m]   : acc[m+8];
                acc[m] = mine + __shfl_xor(send, 8, 64);
            }
        }
        {
            int sel = (kg >> 2) & 1;
#pragma unroll
            for (int m = 0; m < 4; ++m) {
                float mine = sel ? acc[m+4] : acc[m];
                float send = sel ? acc[m]   : acc[m+4];
                acc[m] = mine + __shfl_xor(send, 4, 64);
            }
        }
        {
            int sel = (kg >> 1) & 1;
#pragma unroll
            for (int m = 0; m < 2; ++m) {
                float mine = sel ? acc[m+2] : acc[m];
                float send = sel ? acc[m]   : acc[m+2];
                acc[m] = mine + __shfl_xor(send, 2, 64);
            }
        }
        {
            int sel = kg & 1;
            float mine = sel ? acc[1] : acc[0];
            float send = sel ? acc[0] : acc[1];
            acc[0] = mine + __shfl_xor(send, 1, 64);
        }

        // ---- add x-projection, stash gate value
        {
            int i = kg >> 2, j = kg & 3;
            int b = 8 * bq + 4 * bgl + j;
            int row = 512 * gate + hid0 + i;
            float gv = acc[0] +
                xp[(size_t)(t - t0) * (BATCH * GATES) + (size_t)b * GATES + row];
            gbuf[gate][lane] = gv;
        }
        __syncthreads();

        // ---- elementwise LSTM cell (64 threads: one per (hid_i, b_j) slot)
        if (tid < 64) {
            float iv = gbuf[0][tid];
            float fv = gbuf[1][tid];
            float gv = gbuf[2][tid];
            float ov = gbuf[3][tid];
            iv = 1.f / (1.f + expf(-iv));
            fv = 1.f / (1.f + expf(-fv));
            ov = 1.f / (1.f + expf(-ov));
            gv = tanhf(gv);
            float cn = fv * c_reg + iv * gv;
            float hn = ov * tanhf(cn);
            c_reg = cn;
            int j = tid & 3, i = (tid & 31) >> 2;
            int b = 8 * bq + 4 * (tid >> 5) + j;
            int hh = hid0 + i;
            out_hs[(size_t)t * (BATCH * HID) + (size_t)b * HID + hh] = hn;
            hbuf[(size_t)((t + 1) & 1) * 16384 + (size_t)bq * 4096 + hh * 8 + (b & 7)] = hn;
        }
        grid.sync();
    }

    if (tid < 64) {
        int j = tid & 3, i = (tid & 31) >> 2;
        int b = 8 * bq + 4 * (tid >> 5) + j;
        cbuf[(size_t)b * HID + hid0 + i] = c_reg;
    }
}

// ---------------------------------------------------------------------------
__global__ void init_kernel(const float* __restrict__ h0,
                            const float* __restrict__ c0,
                            float* __restrict__ hbuf,
                            float* __restrict__ cbuf)
{
    int idx = blockIdx.x * 256 + threadIdx.x;
    if (idx < BATCH * HID) {
        int b = idx >> 9, hid = idx & 511;
        hbuf[(size_t)(b >> 3) * 4096 + hid * 8 + (b & 7)] = h0[idx]; // buffer 0
        cbuf[idx] = c0[idx];
    }
}

__global__ void tail_kernel(const float* __restrict__ hbuf,  // buffer (SEQ&1)=0
                            const float* __restrict__ cbuf,
                            float* __restrict__ out)
{
    int idx = blockIdx.x * 256 + threadIdx.x;
    if (idx < BATCH * HID) {
        int b = idx >> 9, hid = idx & 511;
        out[(size_t)SEQ * BATCH * HID + idx] =
            hbuf[(size_t)(b >> 3) * 4096 + hid * 8 + (b & 7)];
        out[(size_t)SEQ * BATCH * HID + BATCH * HID + idx] = cbuf[idx];
    }
}

// ---------------------------------------------------------------------------
extern "C" void kernel_launch(void* const* d_in, const int* in_sizes, int n_in,
                              void* d_out, int out_size, void* d_ws, size_t ws_size,
                              hipStream_t stream)
{
    const float* x   = (const float*)d_in[0];
    const float* h0  = (const float*)d_in[1];
    const float* c0  = (const float*)d_in[2];
    const float* Wih = (const float*)d_in[3];
    const float* Whh = (const float*)d_in[4];
    const float* bih = (const float*)d_in[5];
    const float* bhh = (const float*)d_in[6];
    float* out = (float*)d_out;

    float* hbuf = (float*)d_ws;              // 2*16384 floats
    float* cbuf = hbuf + 2 * 16384;          // 16384 floats
    float* xp   = cbuf + 16384;              // chunk * 65536 floats
    size_t used_floats = 3 * 16384;
    size_t avail = (ws_size / 4 > used_floats) ? (ws_size / 4 - used_floats) : 0;
    int chunk = (int)((avail / (size_t)(BATCH * GATES)));
    if (chunk > SEQ) chunk = SEQ;
    chunk &= ~3;
    if (chunk < 4) chunk = 4;   // minimum viable; assumes ws >= ~1.2 MB

    hipLaunchKernelGGL(init_kernel, dim3(64), dim3(256), 0, stream,
                       h0, c0, hbuf, cbuf);

    for (int t0 = 0; t0 < SEQ; t0 += chunk) {
        int n = SEQ - t0; if (n > chunk) n = chunk;
        int M = n * BATCH;
        hipLaunchKernelGGL(xproj_kernel, dim3(16 * (M / 128)), dim3(256), 0, stream,
                           x + (size_t)t0 * BATCH * IN_DIM, Wih, bih, bhh, xp, M);

        const float* xp_c = xp;
        int t0_arg = t0, n_arg = n;
        void* args[] = { (void*)&Whh, (void*)&xp_c, (void*)&hbuf, (void*)&cbuf,
                         (void*)&out, (void*)&t0_arg, (void*)&n_arg };
        hipLaunchCooperativeKernel((void*)lstm_coop, dim3(256), dim3(256),
                                   args, 0, stream);
    }

    hipLaunchKernelGGL(tail_kernel, dim3(64), dim3(256), 0, stream,
                       hbuf, cbuf, out);
}

// Round 2
// 17874.190 us; speedup vs baseline: 3.8174x; 3.8174x over previous
//
#include <hip/hip_runtime.h>
#include <math.h>

#define SEQ    2048
#define BATCH  32
#define IN_DIM 512
#define HID    512
#define GATES  (4*HID)   // 2048

typedef __attribute__((ext_vector_type(4))) float f32x4;

// ---------------------------------------------------------------------------
// x_proj GEMM:  xp[m][n] = sum_k x[m][k]*Wih[n][k] + bih[n] + bhh[n]
// m = t*32+b (chunk-local), NT layout. 128x128 tile, 8x8 microtile, K=16.
// ---------------------------------------------------------------------------
__global__ __launch_bounds__(256) void xproj_kernel(
    const float* __restrict__ x,     // [M][512]
    const float* __restrict__ Wih,   // [2048][512]
    const float* __restrict__ bih,
    const float* __restrict__ bhh,
    float* __restrict__ xp,          // [M][2048]
    int M)
{
    __shared__ float As[16][132];
    __shared__ float Bs[16][132];
    const int tid = threadIdx.x;
    const int nb = blockIdx.x & 15;
    const int mb = blockIdx.x >> 4;
    const int m0 = mb * 128, n0 = nb * 128;
    const int tx = tid & 15, ty = tid >> 4;

    float acc[8][8];
#pragma unroll
    for (int i = 0; i < 8; ++i)
#pragma unroll
        for (int j = 0; j < 8; ++j) acc[i][j] = 0.f;

    for (int kc = 0; kc < 512; kc += 16) {
#pragma unroll
        for (int h = 0; h < 2; ++h) {
            int f4 = tid + 256 * h;
            int r = f4 >> 2, u = f4 & 3;
            float4 va = *(const float4*)(x + (size_t)(m0 + r) * 512 + kc + 4 * u);
            As[4*u+0][r] = va.x; As[4*u+1][r] = va.y;
            As[4*u+2][r] = va.z; As[4*u+3][r] = va.w;
            float4 vb = *(const float4*)(Wih + (size_t)(n0 + r) * 512 + kc + 4 * u);
            Bs[4*u+0][r] = vb.x; Bs[4*u+1][r] = vb.y;
            Bs[4*u+2][r] = vb.z; Bs[4*u+3][r] = vb.w;
        }
        __syncthreads();
#pragma unroll
        for (int kk = 0; kk < 16; ++kk) {
            float4 a0 = *(const float4*)&As[kk][tx * 8];
            float4 a1 = *(const float4*)&As[kk][tx * 8 + 4];
            float4 b0 = *(const float4*)&Bs[kk][ty * 8];
            float4 b1 = *(const float4*)&Bs[kk][ty * 8 + 4];
            float av[8] = {a0.x,a0.y,a0.z,a0.w,a1.x,a1.y,a1.z,a1.w};
            float bv[8] = {b0.x,b0.y,b0.z,b0.w,b1.x,b1.y,b1.z,b1.w};
#pragma unroll
            for (int i = 0; i < 8; ++i)
#pragma unroll
                for (int j = 0; j < 8; ++j) acc[i][j] += av[i] * bv[j];
        }
        __syncthreads();
    }

    float bias[8];
#pragma unroll
    for (int j = 0; j < 8; ++j) {
        int n = n0 + ty * 8 + j;
        bias[j] = bih[n] + bhh[n];
    }
#pragma unroll
    for (int i = 0; i < 8; ++i) {
        size_t base = (size_t)(m0 + tx * 8 + i) * GATES + n0 + ty * 8;
        float4 v0 = make_float4(acc[i][0]+bias[0], acc[i][1]+bias[1],
                                acc[i][2]+bias[2], acc[i][3]+bias[3]);
        float4 v1 = make_float4(acc[i][4]+bias[4], acc[i][5]+bias[5],
                                acc[i][6]+bias[6], acc[i][7]+bias[7]);
        *(float4*)(xp + base)     = v0;
        *(float4*)(xp + base + 4) = v1;
    }
}

// ---------------------------------------------------------------------------
// h exchange layout (per parity, per batch-quarter bq): 4096 dwords.
// float4 slot q = s*64 + l  (s in [0,16), l in [0,64)) holds
//   h[k = 16*(l&31) + s][b = 8*bq + 4*(l>>5) + j],  j = dword within slot.
// So consumer lane l at micro-step s reads f4 q = s*64+l: stride-1 across the
// wave -> conflict-free ds_read_b128, and staging is an identity copy.
// Producer of h[k][b]: d = 4*((k&15)*64 + 32*((b&7)>>2) + (k>>4)) + (b&3).
// All cross-WG traffic uses agent-scope (sc0 sc1) ops -> coherent at L3,
// no cache-flush fences anywhere.
// ---------------------------------------------------------------------------

__device__ inline void load4_sc01(const float* g0, const float* g1,
                                  const float* g2, const float* g3,
                                  f32x4& a, f32x4& b, f32x4& c, f32x4& d)
{
    asm volatile(
        "global_load_dwordx4 %0, %4, off sc0 sc1\n\t"
        "global_load_dwordx4 %1, %5, off sc0 sc1\n\t"
        "global_load_dwordx4 %2, %6, off sc0 sc1\n\t"
        "global_load_dwordx4 %3, %7, off sc0 sc1\n\t"
        "s_waitcnt vmcnt(0)"
        : "=&v"(a), "=&v"(b), "=&v"(c), "=&v"(d)
        : "v"(g0), "v"(g1), "v"(g2), "v"(g3)
        : "memory");
}

__global__ __launch_bounds__(256, 1) void lstm_coop(
    const float* __restrict__ Whh,   // [2048][512]
    const float* __restrict__ xp,    // [nsteps][32][2048]
    float* __restrict__ hbuf,        // [2][4][4096] permuted layout
    float* __restrict__ cbuf,        // [32][512]
    unsigned* __restrict__ flags,    // [256] stride 16
    unsigned* __restrict__ epoch,    // [1]
    float* __restrict__ out_hs,      // [2048][32][512]
    int t0, int nsteps)
{
    const int w    = blockIdx.x;
    const int a    = w >> 2;
    const int bq   = w & 3;
    const int tid  = threadIdx.x;
    const int gate = tid >> 6;
    const int lane = tid & 63;
    const int bgl  = lane >> 5;
    const int kg   = lane & 31;
    const int hid0 = 8 * a;

    __shared__ float h_lds[4096];
    __shared__ float gbuf[4][64];

    // W_hh slice in registers: 8 rows x 16 k, plain order.
    float wreg[8][16];
#pragma unroll
    for (int i = 0; i < 8; ++i) {
        const float* wr = Whh + (size_t)(512 * gate + hid0 + i) * 512 + 16 * kg;
#pragma unroll
        for (int s = 0; s < 16; ++s) wreg[i][s] = wr[s];
    }

    float c_reg = 0.f;
    if (tid < 64) {
        int i = (tid & 31) >> 2, j = tid & 3;
        int b = 8 * bq + 4 * (tid >> 5) + j;
        c_reg = cbuf[(size_t)b * HID + hid0 + i];
    }

    for (int t = t0; t < t0 + nsteps; ++t) {
        // ---- stage h_t (identity copy, L2-bypass loads, stride-1 LDS writes)
        const float* hsrc = hbuf + (size_t)(t & 1) * 16384 + (size_t)bq * 4096;
        {
            f32x4 v0, v1, v2, v3;
            load4_sc01(hsrc + 4 * (0 * 256 + tid), hsrc + 4 * (1 * 256 + tid),
                       hsrc + 4 * (2 * 256 + tid), hsrc + 4 * (3 * 256 + tid),
                       v0, v1, v2, v3);
            *(f32x4*)&h_lds[4 * (0 * 256 + tid)] = v0;
            *(f32x4*)&h_lds[4 * (1 * 256 + tid)] = v1;
            *(f32x4*)&h_lds[4 * (2 * 256 + tid)] = v2;
            *(f32x4*)&h_lds[4 * (3 * 256 + tid)] = v3;
        }
        // prefetch xp value for this thread (regular cached load, used late)
        const int xrow = 512 * gate + hid0 + (kg >> 2);
        const int xb   = 8 * bq + 4 * bgl + (kg & 3);
        float xpv = xp[(size_t)(t - t0) * (BATCH * GATES) + (size_t)xb * GATES + xrow];
        __syncthreads();

        // ---- dot: 16 conflict-free ds_read_b128 + 512 FMA
        float acc[32];
#pragma unroll
        for (int m = 0; m < 32; ++m) acc[m] = 0.f;
#pragma unroll
        for (int s = 0; s < 16; ++s) {
            f32x4 hv = *(const f32x4*)&h_lds[4 * (s * 64 + lane)];
#pragma unroll
            for (int i = 0; i < 8; ++i) {
                acc[i*4+0] += wreg[i][s] * hv[0];
                acc[i*4+1] += wreg[i][s] * hv[1];
                acc[i*4+2] += wreg[i][s] * hv[2];
                acc[i*4+3] += wreg[i][s] * hv[3];
            }
        }

        // ---- index-descending butterfly: lane kg ends with sum of acc[kg]
        {
            int sel = (kg >> 4) & 1;
#pragma unroll
            for (int m = 0; m < 16; ++m) {
                float mine = sel ? acc[m+16] : acc[m];
                float send = sel ? acc[m]    : acc[m+16];
                acc[m] = mine + __shfl_xor(send, 16, 64);
            }
        }
        {
            int sel = (kg >> 3) & 1;
#pragma unroll
            for (int m = 0; m < 8; ++m) {
                float mine = sel ? acc[m+8] : acc[m];
                float send = sel ? acc[m]   : acc[m+8];
                acc[m] = mine + __shfl_xor(send, 8, 64);
            }
        }
        {
            int sel = (kg >> 2) & 1;
#pragma unroll
            for (int m = 0; m < 4; ++m) {
                float mine = sel ? acc[m+4] : acc[m];
                float send = sel ? acc[m]   : acc[m+4];
                acc[m] = mine + __shfl_xor(send, 4, 64);
            }
        }
        {
            int sel = (kg >> 1) & 1;
#pragma unroll
            for (int m = 0; m < 2; ++m) {
                float mine = sel ? acc[m+2] : acc[m];
                float send = sel ? acc[m]   : acc[m+2];
                acc[m] = mine + __shfl_xor(send, 2, 64);
            }
        }
        {
            int sel = kg & 1;
            float mine = sel ? acc[1] : acc[0];
            float send = sel ? acc[0] : acc[1];
            acc[0] = mine + __shfl_xor(send, 1, 64);
        }

        gbuf[gate][lane] = acc[0] + xpv;
        __syncthreads();

        // ---- elementwise tail (wave 0 only) + h publication
        if (tid < 64) {
            float iv = gbuf[0][tid];
            float fv = gbuf[1][tid];
            float gv = gbuf[2][tid];
            float ov = gbuf[3][tid];
            iv = 1.f / (1.f + expf(-iv));
            fv = 1.f / (1.f + expf(-fv));
            ov = 1.f / (1.f + expf(-ov));
            gv = tanhf(gv);
            float cn = fv * c_reg + iv * gv;
            float hn = ov * tanhf(cn);
            c_reg = cn;
            int j = tid & 3, i = (tid & 31) >> 2;
            int b  = 8 * bq + 4 * (tid >> 5) + j;
            int hh = hid0 + i;
            out_hs[(size_t)t * (BATCH * HID) + (size_t)b * HID + hh] = hn;
            int d = 4 * ((hh & 15) * 64 + 32 * (tid >> 5) + (hh >> 4)) + j;
            __hip_atomic_store(
                &hbuf[(size_t)((t + 1) & 1) * 16384 + (size_t)bq * 4096 + d],
                hn, __ATOMIC_RELAXED, __HIP_MEMORY_SCOPE_AGENT);
        }
        // wave 0 lane 0: publish arrival (release waits wave-0 vmcnt)
        if (tid == 0)
            __hip_atomic_store(&flags[w * 16], (unsigned)(t + 1),
                               __ATOMIC_RELEASE, __HIP_MEMORY_SCOPE_AGENT);

        if (w == 0) {
            __syncthreads();   // all 256 checker threads ready
            while (__hip_atomic_load(&flags[tid * 16], __ATOMIC_RELAXED,
                                     __HIP_MEMORY_SCOPE_AGENT) < (unsigned)(t + 1))
                __builtin_amdgcn_s_sleep(1);
            __syncthreads();   // all flags seen
            if (tid == 0)
                __hip_atomic_store(epoch, (unsigned)(t + 1),
                                   __ATOMIC_RELEASE, __HIP_MEMORY_SCOPE_AGENT);
        } else {
            if (lane == 0) {
                while (__hip_atomic_load(epoch, __ATOMIC_RELAXED,
                                         __HIP_MEMORY_SCOPE_AGENT) < (unsigned)(t + 1))
                    __builtin_amdgcn_s_sleep(2);
            }
            // wave reconverges; all 4 waves individually gated by epoch
        }
    }

    if (tid < 64) {
        int j = tid & 3, i = (tid & 31) >> 2;
        int b = 8 * bq + 4 * (tid >> 5) + j;
        cbuf[(size_t)b * HID + hid0 + i] = c_reg;
    }
}

// ---------------------------------------------------------------------------
__global__ void init_kernel(const float* __restrict__ h0,
                            const float* __restrict__ c0,
                            float* __restrict__ hbuf,
                            float* __restrict__ cbuf,
                            unsigned* __restrict__ flags)  // 4096 + 16 words
{
    int idx = blockIdx.x * 256 + threadIdx.x;
    if (idx < BATCH * HID) {
        int b = idx >> 9, k = idx & 511;
        int d = 4 * ((k & 15) * 64 + 32 * ((b & 7) >> 2) + (k >> 4)) + (b & 3);
        hbuf[(size_t)(b >> 3) * 4096 + d] = h0[idx];   // parity 0
        cbuf[idx] = c0[idx];
    }
    if (idx < 4112) flags[idx] = 0u;
}

__global__ void tail_kernel(const float* __restrict__ hbuf,  // parity 0
                            const float* __restrict__ cbuf,
                            float* __restrict__ out)
{
    int idx = blockIdx.x * 256 + threadIdx.x;
    if (idx < BATCH * HID) {
        int b = idx >> 9, k = idx & 511;
        int d = 4 * ((k & 15) * 64 + 32 * ((b & 7) >> 2) + (k >> 4)) + (b & 3);
        out[(size_t)SEQ * BATCH * HID + idx] = hbuf[(size_t)(b >> 3) * 4096 + d];
        out[(size_t)SEQ * BATCH * HID + BATCH * HID + idx] = cbuf[idx];
    }
}

// ---------------------------------------------------------------------------
extern "C" void kernel_launch(void* const* d_in, const int* in_sizes, int n_in,
                              void* d_out, int out_size, void* d_ws, size_t ws_size,
                              hipStream_t stream)
{
    const float* x   = (const float*)d_in[0];
    const float* h0  = (const float*)d_in[1];
    const float* c0  = (const float*)d_in[2];
    const float* Wih = (const float*)d_in[3];
    const float* Whh = (const float*)d_in[4];
    const float* bih = (const float*)d_in[5];
    const float* bhh = (const float*)d_in[6];
    float* out = (float*)d_out;

    float*    hbuf  = (float*)d_ws;                 // 2*4*4096 = 32768 floats
    float*    cbuf  = hbuf + 32768;                 // 16384 floats
    unsigned* flags = (unsigned*)(cbuf + 16384);    // 4096 words
    unsigned* epoch = flags + 4096;                 // 16 words
    float*    xp    = (float*)(epoch + 16);
    size_t used_floats = 32768 + 16384 + 4096 + 16;
    size_t avail = (ws_size / 4 > used_floats) ? (ws_size / 4 - used_floats) : 0;
    int chunk = (int)(avail / (size_t)(BATCH * GATES));
    if (chunk > SEQ) chunk = SEQ;
    chunk &= ~3;
    if (chunk < 4) chunk = 4;

    hipLaunchKernelGGL(init_kernel, dim3(64), dim3(256), 0, stream,
                       h0, c0, hbuf, cbuf, flags);

    for (int t0 = 0; t0 < SEQ; t0 += chunk) {
        int n = SEQ - t0; if (n > chunk) n = chunk;
        int M = n * BATCH;
        hipLaunchKernelGGL(xproj_kernel, dim3(16 * (M / 128)), dim3(256), 0, stream,
                           x + (size_t)t0 * BATCH * IN_DIM, Wih, bih, bhh, xp, M);

        const float* xp_c = xp;
        int t0_arg = t0, n_arg = n;
        void* args[] = { (void*)&Whh, (void*)&xp_c, (void*)&hbuf, (void*)&cbuf,
                         (void*)&flags, (void*)&epoch, (void*)&out,
                         (void*)&t0_arg, (void*)&n_arg };
        hipLaunchCooperativeKernel((void*)lstm_coop, dim3(256), dim3(256),
                                   args, 0, stream);
    }

    hipLaunchKernelGGL(tail_kernel, dim3(64), dim3(256), 0, stream,
                       hbuf, cbuf, out);
}

// Round 3
// 9611.475 us; speedup vs baseline: 7.0990x; 1.8597x over previous
//
#include <hip/hip_runtime.h>
#include <math.h>

#define SEQ    2048
#define BATCH  32
#define IN_DIM 512
#define HID    512
#define GATES  (4*HID)   // 2048

typedef __attribute__((ext_vector_type(4))) float f32x4;

// ---------------------------------------------------------------------------
// x_proj GEMM:  xp[m][n] = sum_k x[m][k]*Wih[n][k] + bih[n] + bhh[n]
// ---------------------------------------------------------------------------
__global__ __launch_bounds__(256) void xproj_kernel(
    const float* __restrict__ x,     // [M][512]
    const float* __restrict__ Wih,   // [2048][512]
    const float* __restrict__ bih,
    const float* __restrict__ bhh,
    float* __restrict__ xp,          // [M][2048]
    int M)
{
    __shared__ float As[16][132];
    __shared__ float Bs[16][132];
    const int tid = threadIdx.x;
    const int nb = blockIdx.x & 15;
    const int mb = blockIdx.x >> 4;
    const int m0 = mb * 128, n0 = nb * 128;
    const int tx = tid & 15, ty = tid >> 4;

    float acc[8][8];
#pragma unroll
    for (int i = 0; i < 8; ++i)
#pragma unroll
        for (int j = 0; j < 8; ++j) acc[i][j] = 0.f;

    for (int kc = 0; kc < 512; kc += 16) {
#pragma unroll
        for (int h = 0; h < 2; ++h) {
            int f4 = tid + 256 * h;
            int r = f4 >> 2, u = f4 & 3;
            float4 va = *(const float4*)(x + (size_t)(m0 + r) * 512 + kc + 4 * u);
            As[4*u+0][r] = va.x; As[4*u+1][r] = va.y;
            As[4*u+2][r] = va.z; As[4*u+3][r] = va.w;
            float4 vb = *(const float4*)(Wih + (size_t)(n0 + r) * 512 + kc + 4 * u);
            Bs[4*u+0][r] = vb.x; Bs[4*u+1][r] = vb.y;
            Bs[4*u+2][r] = vb.z; Bs[4*u+3][r] = vb.w;
        }
        __syncthreads();
#pragma unroll
        for (int kk = 0; kk < 16; ++kk) {
            float4 a0 = *(const float4*)&As[kk][tx * 8];
            float4 a1 = *(const float4*)&As[kk][tx * 8 + 4];
            float4 b0 = *(const float4*)&Bs[kk][ty * 8];
            float4 b1 = *(const float4*)&Bs[kk][ty * 8 + 4];
            float av[8] = {a0.x,a0.y,a0.z,a0.w,a1.x,a1.y,a1.z,a1.w};
            float bv[8] = {b0.x,b0.y,b0.z,b0.w,b1.x,b1.y,b1.z,b1.w};
#pragma unroll
            for (int i = 0; i < 8; ++i)
#pragma unroll
                for (int j = 0; j < 8; ++j) acc[i][j] += av[i] * bv[j];
        }
        __syncthreads();
    }

    float bias[8];
#pragma unroll
    for (int j = 0; j < 8; ++j) {
        int n = n0 + ty * 8 + j;
        bias[j] = bih[n] + bhh[n];
    }
#pragma unroll
    for (int i = 0; i < 8; ++i) {
        size_t base = (size_t)(m0 + tx * 8 + i) * GATES + n0 + ty * 8;
        float4 v0 = make_float4(acc[i][0]+bias[0], acc[i][1]+bias[1],
                                acc[i][2]+bias[2], acc[i][3]+bias[3]);
        float4 v1 = make_float4(acc[i][4]+bias[4], acc[i][5]+bias[5],
                                acc[i][6]+bias[6], acc[i][7]+bias[7]);
        *(float4*)(xp + base)     = v0;
        *(float4*)(xp + base + 4) = v1;
    }
}

// ---------------------------------------------------------------------------
// Scan: 8 independent groups (4 batches each) of 32 WGs. Per group & parity,
// h region = 2048 floats: f4 slot(k) = 16*(k&31) + (k>>5), component = b&3.
// Consumer lane (hid_h,kg) at micro-step s reads slot 16*s+kg  (k = 32*kg+s).
// All cross-WG data via raw sc0 sc1 (LLC write-through) ops; ordering via
// s_waitcnt vmcnt(0) between h stores and flag store. No cache maintenance.
// ---------------------------------------------------------------------------
__global__ __launch_bounds__(256, 1) void lstm_coop(
    const float* __restrict__ Whh,   // [2048][512]
    const float* __restrict__ xp,    // [nsteps][32][2048]
    float* __restrict__ hbuf,        // [2][8][2048] floats, slot layout
    float* __restrict__ cbuf,        // [32][512]
    unsigned* __restrict__ flags,    // [8][32] stride 32 dwords
    float* __restrict__ out_hs,      // [2048][32][512]
    int t0, int nsteps)
{
    const int w    = blockIdx.x;
    const int g    = w >> 5;         // batch-quad group [0,8)
    const int sl   = w & 31;         // slot in group -> hid slice [0,32)
    const int tid  = threadIdx.x;
    const int gate = tid >> 6;
    const int lane = tid & 63;
    const int hid_h = lane >> 4;     // [0,4)
    const int kg    = lane & 15;     // [0,16) k-split (chunk 32)
    const int hid0  = 16 * sl;
    const int B0    = 4 * g;

    __shared__ f32x4 h4[512];        // group h in slot order
    __shared__ float gbuf[4][64];

    // W_hh slice: 4 rows (4 hid of our gate) x 32 k  = 128 floats in regs
    float wreg[4][32];
#pragma unroll
    for (int i = 0; i < 4; ++i) {
        const float* wr = Whh + (size_t)(512 * gate + hid0 + 4 * hid_h + i) * 512
                          + 32 * kg;
#pragma unroll
        for (int q = 0; q < 8; ++q) {
            float4 v = *(const float4*)(wr + 4 * q);
            wreg[i][4*q+0] = v.x; wreg[i][4*q+1] = v.y;
            wreg[i][4*q+2] = v.z; wreg[i][4*q+3] = v.w;
        }
    }

    float c_reg = 0.f;
    if (tid < 64) {
        int hid_local = 4 * (tid >> 4) + ((tid >> 2) & 3);
        int b_j = tid & 3;
        c_reg = cbuf[(size_t)(B0 + b_j) * HID + hid0 + hid_local];
    }

    unsigned* const gflags = flags + g * 1024;          // 32 slots * stride 32

    for (int t = t0; t < t0 + nsteps; ++t) {
        // xp prefetch (independent of h)
        const int xrow = 512 * gate + hid0 + 4 * hid_h + (kg >> 2);
        const int xb   = B0 + (kg & 3);
        float xpv = xp[(size_t)(t - t0) * (BATCH * GATES)
                       + (size_t)xb * GATES + xrow];

        // ---- flat 1-hop barrier: every wave polls all 32 group flags >= t
        {
            const unsigned* fp = gflags + (lane & 31) * 32;
            const unsigned target = (unsigned)t;
            while (true) {
                unsigned v;
                asm volatile("global_load_dword %0, %1, off sc0 sc1\n\t"
                             "s_waitcnt vmcnt(0)"
                             : "=&v"(v) : "v"(fp) : "memory");
                bool stale = (lane < 32) && (v < target);
                if (__ballot(stale) == 0ull) break;
                __builtin_amdgcn_s_sleep(1);
            }
        }

        // ---- stage group h (identity copy, LLC loads)
        {
            const float* hsrc = hbuf + ((size_t)(t & 1) * 8 + g) * 2048;
            f32x4 v0, v1;
            asm volatile("global_load_dwordx4 %0, %2, off sc0 sc1\n\t"
                         "global_load_dwordx4 %1, %3, off sc0 sc1\n\t"
                         "s_waitcnt vmcnt(0)"
                         : "=&v"(v0), "=&v"(v1)
                         : "v"(hsrc + 4 * tid), "v"(hsrc + 4 * (tid + 256))
                         : "memory");
            h4[tid]       = v0;
            h4[tid + 256] = v1;
        }
        __syncthreads();

        // ---- dot: 32 x (ds_read_b128 + 16 FMA)  -> acc[4*hid_i + b_j]
        float acc[16];
#pragma unroll
        for (int m = 0; m < 16; ++m) acc[m] = 0.f;
#pragma unroll
        for (int s = 0; s < 32; ++s) {
            f32x4 hv = h4[16 * s + kg];
#pragma unroll
            for (int i = 0; i < 4; ++i) {
                acc[4*i+0] += wreg[i][s] * hv[0];
                acc[4*i+1] += wreg[i][s] * hv[1];
                acc[4*i+2] += wreg[i][s] * hv[2];
                acc[4*i+3] += wreg[i][s] * hv[3];
            }
        }

        // ---- index-descending butterfly over kg (4 stages): lane kg -> acc[kg]
        {
            int sel = (kg >> 3) & 1;
#pragma unroll
            for (int m = 0; m < 8; ++m) {
                float mine = sel ? acc[m+8] : acc[m];
                float send = sel ? acc[m]   : acc[m+8];
                acc[m] = mine + __shfl_xor(send, 8, 64);
            }
        }
        {
            int sel = (kg >> 2) & 1;
#pragma unroll
            for (int m = 0; m < 4; ++m) {
                float mine = sel ? acc[m+4] : acc[m];
                float send = sel ? acc[m]   : acc[m+4];
                acc[m] = mine + __shfl_xor(send, 4, 64);
            }
        }
        {
            int sel = (kg >> 1) & 1;
#pragma unroll
            for (int m = 0; m < 2; ++m) {
                float mine = sel ? acc[m+2] : acc[m];
                float send = sel ? acc[m]   : acc[m+2];
                acc[m] = mine + __shfl_xor(send, 2, 64);
            }
        }
        {
            int sel = kg & 1;
            float mine = sel ? acc[1] : acc[0];
            float send = sel ? acc[0] : acc[1];
            acc[0] = mine + __shfl_xor(send, 1, 64);
        }

        gbuf[gate][lane] = acc[0] + xpv;
        __syncthreads();

        // ---- elementwise tail (wave 0) + publish h + flag
        if (tid < 64) {
            float iv = gbuf[0][tid];
            float fv = gbuf[1][tid];
            float gv = gbuf[2][tid];
            float ov = gbuf[3][tid];
            iv = 1.f / (1.f + expf(-iv));
            fv = 1.f / (1.f + expf(-fv));
            ov = 1.f / (1.f + expf(-ov));
            gv = tanhf(gv);
            float cn = fv * c_reg + iv * gv;
            float hn = ov * tanhf(cn);
            c_reg = cn;

            int hid_local = 4 * (tid >> 4) + ((tid >> 2) & 3);
            int b_j = tid & 3;
            int k = hid0 + hid_local;
            int slot = 16 * (k & 31) + (k >> 5);
            float* hp = hbuf + ((size_t)((t + 1) & 1) * 8 + g) * 2048
                        + 4 * slot + b_j;
            asm volatile("global_store_dword %0, %1, off sc0 sc1"
                         :: "v"(hp), "v"(hn) : "memory");
            asm volatile("s_waitcnt vmcnt(0)" ::: "memory");
            if (tid == 0) {
                unsigned fv2 = (unsigned)(t + 1);
                unsigned* fp = gflags + sl * 32;
                asm volatile("global_store_dword %0, %1, off sc0 sc1"
                             :: "v"(fp), "v"(fv2) : "memory");
            }
            // off-critical-path output store (after flag)
            out_hs[(size_t)t * (BATCH * HID) + (size_t)(B0 + b_j) * HID + k] = hn;
        }
        // no further barrier: next-iteration poll gates everything
    }

    if (tid < 64) {
        int hid_local = 4 * (tid >> 4) + ((tid >> 2) & 3);
        int b_j = tid & 3;
        cbuf[(size_t)(B0 + b_j) * HID + hid0 + hid_local] = c_reg;
    }
}

// ---------------------------------------------------------------------------
__global__ void init_kernel(const float* __restrict__ h0,
                            const float* __restrict__ c0,
                            float* __restrict__ hbuf,
                            float* __restrict__ cbuf,
                            unsigned* __restrict__ flags)
{
    int idx = blockIdx.x * 256 + threadIdx.x;
    if (idx < BATCH * HID) {
        int b = idx >> 9, k = idx & 511;
        int g = b >> 2, b_j = b & 3;
        int slot = 16 * (k & 31) + (k >> 5);
        hbuf[(size_t)g * 2048 + 4 * slot + b_j] = h0[idx];   // parity 0
        cbuf[idx] = c0[idx];
    }
    if (idx < 8192) flags[idx] = 0u;
}

__global__ void tail_kernel(const float* __restrict__ hbuf,  // parity 0
                            const float* __restrict__ cbuf,
                            float* __restrict__ out)
{
    int idx = blockIdx.x * 256 + threadIdx.x;
    if (idx < BATCH * HID) {
        int b = idx >> 9, k = idx & 511;
        int g = b >> 2, b_j = b & 3;
        int slot = 16 * (k & 31) + (k >> 5);
        out[(size_t)SEQ * BATCH * HID + idx] =
            hbuf[(size_t)g * 2048 + 4 * slot + b_j];
        out[(size_t)SEQ * BATCH * HID + BATCH * HID + idx] = cbuf[idx];
    }
}

// ---------------------------------------------------------------------------
extern "C" void kernel_launch(void* const* d_in, const int* in_sizes, int n_in,
                              void* d_out, int out_size, void* d_ws, size_t ws_size,
                              hipStream_t stream)
{
    const float* x   = (const float*)d_in[0];
    const float* h0  = (const float*)d_in[1];
    const float* c0  = (const float*)d_in[2];
    const float* Wih = (const float*)d_in[3];
    const float* Whh = (const float*)d_in[4];
    const float* bih = (const float*)d_in[5];
    const float* bhh = (const float*)d_in[6];
    float* out = (float*)d_out;

    float*    hbuf  = (float*)d_ws;                 // 2*8*2048 = 32768 floats
    float*    cbuf  = hbuf + 32768;                 // 16384 floats
    unsigned* flags = (unsigned*)(cbuf + 16384);    // 8192 words
    float*    xp    = (float*)(flags + 8192);
    size_t used_floats = 32768 + 16384 + 8192;
    size_t avail = (ws_size / 4 > used_floats) ? (ws_size / 4 - used_floats) : 0;
    int chunk = (int)(avail / (size_t)(BATCH * GATES));
    if (chunk > SEQ) chunk = SEQ;
    chunk &= ~3;
    if (chunk < 4) chunk = 4;

    hipLaunchKernelGGL(init_kernel, dim3(64), dim3(256), 0, stream,
                       h0, c0, hbuf, cbuf, flags);

    for (int t0 = 0; t0 < SEQ; t0 += chunk) {
        int n = SEQ - t0; if (n > chunk) n = chunk;
        int M = n * BATCH;
        hipLaunchKernelGGL(xproj_kernel, dim3(16 * (M / 128)), dim3(256), 0, stream,
                           x + (size_t)t0 * BATCH * IN_DIM, Wih, bih, bhh, xp, M);

        const float* xp_c = xp;
        int t0_arg = t0, n_arg = n;
        void* args[] = { (void*)&Whh, (void*)&xp_c, (void*)&hbuf, (void*)&cbuf,
                         (void*)&flags, (void*)&out, (void*)&t0_arg, (void*)&n_arg };
        hipLaunchCooperativeKernel((void*)lstm_coop, dim3(256), dim3(256),
                                   args, 0, stream);
    }

    hipLaunchKernelGGL(tail_kernel, dim3(64), dim3(256), 0, stream,
                       hbuf, cbuf, out);
}